// Round 1
// 230.689 us; speedup vs baseline: 1.0329x; 1.0329x over previous
//
#include <hip/hip_runtime.h>
#include <hip/hip_bf16.h>

#define D 64
#define THREADS 256
#define BKT_BITS 9                 // 512 nodes per bucket
#define BKT_NODES (1 << BKT_BITS)
#define CHUNK 8192                 // edges per pass-1 block

// ---- bf16 helpers (bit tricks, RNE) ----
__device__ __forceinline__ unsigned f2bf(float f) {
    unsigned u = __float_as_uint(f);
    return (u + 0x7fffu + ((u >> 16) & 1u)) >> 16;
}
__device__ __forceinline__ float2 bfpair(unsigned v) {
    return make_float2(__uint_as_float(v << 16), __uint_as_float(v & 0xffff0000u));
}

// ---- p1a: per-chunk LDS histogram of coarse buckets (B <= 256) ----
__global__ void p1a_hist(const int* __restrict__ dst, int* __restrict__ blockCount,
                         int E, int B) {
    __shared__ int lc[256];
    int t = threadIdx.x;
    lc[t] = 0;
    __syncthreads();
    int base = blockIdx.x * CHUNK;
    int end = min(base + CHUNK, E);
    for (int e = base + t; e < end; e += THREADS)
        atomicAdd(&lc[dst[e] >> BKT_BITS], 1);
    __syncthreads();
    if (t < B) blockCount[(long long)blockIdx.x * B + t] = lc[t];
}

// ---- p1b: per-bucket exclusive scan over blocks (in place) + bucket totals ----
__global__ void p1b_scanblocks(int* __restrict__ blockCount, int* __restrict__ total,
                               int NBLK, int B) {
    __shared__ int sm[256];
    int b = blockIdx.x, t = threadIdx.x;
    int run = 0;
    for (int base = 0; base < NBLK; base += 256) {
        int i = base + t;
        int v = (i < NBLK) ? blockCount[(long long)i * B + b] : 0;
        sm[t] = v;
        __syncthreads();
        for (int off = 1; off < 256; off <<= 1) {
            int u = (t >= off) ? sm[t - off] : 0;
            __syncthreads();
            sm[t] += u;
            __syncthreads();
        }
        if (i < NBLK) blockCount[(long long)i * B + b] = run + sm[t] - v;
        run += sm[255];
        __syncthreads();
    }
    if (t == 0) total[b] = run;
}

// ---- p1c: exclusive scan of bucket totals -> bstart[B+1] ----
__global__ void p1c_scanbuckets(const int* __restrict__ total, int* __restrict__ bstart,
                                int B, int E) {
    __shared__ int sm[256];
    int t = threadIdx.x;
    int run = 0;
    for (int base = 0; base < B; base += 256) {
        int i = base + t;
        int v = (i < B) ? total[i] : 0;
        sm[t] = v;
        __syncthreads();
        for (int off = 1; off < 256; off <<= 1) {
            int u = (t >= off) ? sm[t - off] : 0;
            __syncthreads();
            sm[t] += u;
            __syncthreads();
        }
        if (i < B) bstart[i] = run + sm[t] - v;
        run += sm[255];
        __syncthreads();
    }
    if (t == 0) bstart[B] = E;
}

// ---- p1d: scatter edges into bucket-partitioned temp via LDS cursors ----
// temp[pos] = (src | dstlow<<17, w)   [src < 2^17 since N=100k]
__global__ void p1d_scatter(const int* __restrict__ dst, const int* __restrict__ src,
                            const float* __restrict__ w, const int* __restrict__ blockCount,
                            const int* __restrict__ bstart, int2* __restrict__ temp,
                            int E, int B) {
    __shared__ int cur[256];
    int t = threadIdx.x;
    if (t < B) cur[t] = bstart[t] + blockCount[(long long)blockIdx.x * B + t];
    __syncthreads();
    int base = blockIdx.x * CHUNK;
    int end = min(base + CHUNK, E);
    for (int e = base + t; e < end; e += THREADS) {
        int d = dst[e];
        int b = d >> BKT_BITS;
        int pos = atomicAdd(&cur[b], 1);                       // LDS atomic w/ return
        temp[pos] = make_int2(src[e] | ((d & (BKT_NODES - 1)) << 17),
                              __float_as_int(w[e]));
    }
}

// ---- p2a: per-bucket histogram+deg (LDS) -> scan -> rowptr/norm ----
__global__ void p2a_build(const int2* __restrict__ temp, const int* __restrict__ bstart,
                          int* __restrict__ rowptr, float* __restrict__ norm,
                          int N, int E, int B) {
    __shared__ int cnt[BKT_NODES];
    __shared__ float degs[BKT_NODES];
    __shared__ int sm[256];
    int b = blockIdx.x, t = threadIdx.x;
    int ebeg = bstart[b], eend = bstart[b + 1];
    for (int i = t; i < BKT_NODES; i += THREADS) { cnt[i] = 0; degs[i] = 0.0f; }
    __syncthreads();
    for (int e = ebeg + t; e < eend; e += THREADS) {
        int2 pk = temp[e];
        int dl = (pk.x >> 17) & (BKT_NODES - 1);
        atomicAdd(&cnt[dl], 1);
        atomicAdd(&degs[dl], __int_as_float(pk.y));
    }
    __syncthreads();
    // block exclusive scan of cnt[512]; write rowptr + norm directly
    int node0 = b << BKT_BITS;
    int run = 0;
    for (int base = 0; base < BKT_NODES; base += 256) {
        int v = cnt[base + t];
        sm[t] = v;
        __syncthreads();
        for (int off = 1; off < 256; off <<= 1) {
            int u = (t >= off) ? sm[t - off] : 0;
            __syncthreads();
            sm[t] += u;
            __syncthreads();
        }
        int node = node0 + base + t;
        if (node < N) {
            rowptr[node] = ebeg + run + sm[t] - v;
            norm[node] = rsqrtf(fmaxf(degs[base + t], 1.0f));
        }
        run += sm[255];
        __syncthreads();
    }
    if (b == 0 && t == 0) rowptr[N] = E;
}

// ---- p2b: placement pass; fold coef = w * norm[src] into packed ----
// (norm is globally visible here: separate launch after p2a)
__global__ void p2b_place(const int2* __restrict__ temp, const int* __restrict__ bstart,
                          const int* __restrict__ rowptr, const float* __restrict__ norm,
                          int2* __restrict__ packed, int N, int E) {
    __shared__ int cur[BKT_NODES];
    int b = blockIdx.x, t = threadIdx.x;
    int ebeg = bstart[b], eend = bstart[b + 1];
    int node0 = b << BKT_BITS;
    for (int i = t; i < BKT_NODES; i += THREADS) {
        int node = node0 + i;
        cur[i] = (node < N) ? (rowptr[node] - ebeg) : 0;
    }
    __syncthreads();
    for (int e = ebeg + t; e < eend; e += THREADS) {
        int2 pk = temp[e];
        int dl = (pk.x >> 17) & (BKT_NODES - 1);
        int s = pk.x & 0x1ffff;
        float coef = __int_as_float(pk.y) * norm[s];           // random read, L2-resident (400KB)
        int pos = atomicAdd(&cur[dl], 1);                      // LDS atomic w/ return
        packed[ebeg + pos] = make_int2(s, __float_as_int(coef));
    }
}

// ---- h (fp32) -> bf16 packed pairs, 4 elems/thread ----
__global__ void tobf16_kernel(const float* __restrict__ h, unsigned* __restrict__ hbf2,
                              long long nd4) {
    long long i = (long long)blockIdx.x * blockDim.x + threadIdx.x;
    if (i < nd4) {
        float4 v = ((const float4*)h)[i];
        ((uint2*)hbf2)[i] = make_uint2(f2bf(v.x) | (f2bf(v.y) << 16),
                                       f2bf(v.z) | (f2bf(v.w) << 16));
    }
}

// 8 bf16 dims per lane per edge, coef already folded (packed.y = w*norm[src])
#define EDGE_FMA(r, c, A0, A1, A2, A3, A4, A5, A6, A7) do {            \
    float2 fa = bfpair((r).x), fb = bfpair((r).y);                      \
    float2 fc = bfpair((r).z), fd = bfpair((r).w);                      \
    A0 = fmaf(fa.x, (c), A0); A1 = fmaf(fa.y, (c), A1);                 \
    A2 = fmaf(fb.x, (c), A2); A3 = fmaf(fb.y, (c), A3);                 \
    A4 = fmaf(fc.x, (c), A4); A5 = fmaf(fc.y, (c), A5);                 \
    A6 = fmaf(fd.x, (c), A6); A7 = fmaf(fd.y, (c), A7); } while (0)

// ---- gather layer 1: 8 lanes per node (lane = 8 dims, uint4), unroll 8 ----
__global__ void gather1_kernel(const uint4* __restrict__ h_in, const int2* __restrict__ packed,
                               const int* __restrict__ rowptr, const float* __restrict__ norm,
                               uint4* __restrict__ h_out, int N) {
    int node = blockIdx.x * (blockDim.x >> 3) + (threadIdx.x >> 3);
    int lane = threadIdx.x & 7;
    if (node >= N) return;
    int j = rowptr[node], end = rowptr[node + 1];
    float a0 = 0, a1 = 0, a2 = 0, a3 = 0, a4 = 0, a5 = 0, a6 = 0, a7 = 0;
    float b0 = 0, b1 = 0, b2 = 0, b3 = 0, b4 = 0, b5 = 0, b6 = 0, b7 = 0;
    for (; j + 8 <= end; j += 8) {
        int2 p0 = packed[j + 0], p1 = packed[j + 1], p2 = packed[j + 2], p3 = packed[j + 3];
        int2 p4 = packed[j + 4], p5 = packed[j + 5], p6 = packed[j + 6], p7 = packed[j + 7];
        uint4 r0 = h_in[((long long)p0.x << 3) + lane];
        uint4 r1 = h_in[((long long)p1.x << 3) + lane];
        uint4 r2 = h_in[((long long)p2.x << 3) + lane];
        uint4 r3 = h_in[((long long)p3.x << 3) + lane];
        uint4 r4 = h_in[((long long)p4.x << 3) + lane];
        uint4 r5 = h_in[((long long)p5.x << 3) + lane];
        uint4 r6 = h_in[((long long)p6.x << 3) + lane];
        uint4 r7 = h_in[((long long)p7.x << 3) + lane];
        EDGE_FMA(r0, __int_as_float(p0.y), a0, a1, a2, a3, a4, a5, a6, a7);
        EDGE_FMA(r1, __int_as_float(p1.y), b0, b1, b2, b3, b4, b5, b6, b7);
        EDGE_FMA(r2, __int_as_float(p2.y), a0, a1, a2, a3, a4, a5, a6, a7);
        EDGE_FMA(r3, __int_as_float(p3.y), b0, b1, b2, b3, b4, b5, b6, b7);
        EDGE_FMA(r4, __int_as_float(p4.y), a0, a1, a2, a3, a4, a5, a6, a7);
        EDGE_FMA(r5, __int_as_float(p5.y), b0, b1, b2, b3, b4, b5, b6, b7);
        EDGE_FMA(r6, __int_as_float(p6.y), a0, a1, a2, a3, a4, a5, a6, a7);
        EDGE_FMA(r7, __int_as_float(p7.y), b0, b1, b2, b3, b4, b5, b6, b7);
    }
    for (; j + 4 <= end; j += 4) {
        int2 p0 = packed[j + 0], p1 = packed[j + 1], p2 = packed[j + 2], p3 = packed[j + 3];
        uint4 r0 = h_in[((long long)p0.x << 3) + lane];
        uint4 r1 = h_in[((long long)p1.x << 3) + lane];
        uint4 r2 = h_in[((long long)p2.x << 3) + lane];
        uint4 r3 = h_in[((long long)p3.x << 3) + lane];
        EDGE_FMA(r0, __int_as_float(p0.y), a0, a1, a2, a3, a4, a5, a6, a7);
        EDGE_FMA(r1, __int_as_float(p1.y), b0, b1, b2, b3, b4, b5, b6, b7);
        EDGE_FMA(r2, __int_as_float(p2.y), a0, a1, a2, a3, a4, a5, a6, a7);
        EDGE_FMA(r3, __int_as_float(p3.y), b0, b1, b2, b3, b4, b5, b6, b7);
    }
    for (; j < end; ++j) {
        int2 p = packed[j];
        uint4 r = h_in[((long long)p.x << 3) + lane];
        EDGE_FMA(r, __int_as_float(p.y), a0, a1, a2, a3, a4, a5, a6, a7);
    }
    float nv = norm[node];
    float d0 = (a0 + b0) * nv, d1 = (a1 + b1) * nv, d2 = (a2 + b2) * nv, d3 = (a3 + b3) * nv;
    float d4 = (a4 + b4) * nv, d5 = (a5 + b5) * nv, d6 = (a6 + b6) * nv, d7 = (a7 + b7) * nv;
    h_out[((long long)node << 3) + lane] =
        make_uint4(f2bf(d0) | (f2bf(d1) << 16), f2bf(d2) | (f2bf(d3) << 16),
                   f2bf(d4) | (f2bf(d5) << 16), f2bf(d6) | (f2bf(d7) << 16));
}

// ---- gather layer 2 + mean: out = (h0 + h1 + norm*sum h1[src]*coef)/3 ----
__global__ void gather2_final_kernel(const uint4* __restrict__ h0bf, const uint4* __restrict__ h1bf,
                                     const int2* __restrict__ packed, const int* __restrict__ rowptr,
                                     const float* __restrict__ norm, float* __restrict__ out, int N) {
    int node = blockIdx.x * (blockDim.x >> 3) + (threadIdx.x >> 3);
    int lane = threadIdx.x & 7;
    if (node >= N) return;
    int j = rowptr[node], end = rowptr[node + 1];
    float a0 = 0, a1 = 0, a2 = 0, a3 = 0, a4 = 0, a5 = 0, a6 = 0, a7 = 0;
    float b0 = 0, b1 = 0, b2 = 0, b3 = 0, b4 = 0, b5 = 0, b6 = 0, b7 = 0;
    for (; j + 8 <= end; j += 8) {
        int2 p0 = packed[j + 0], p1 = packed[j + 1], p2 = packed[j + 2], p3 = packed[j + 3];
        int2 p4 = packed[j + 4], p5 = packed[j + 5], p6 = packed[j + 6], p7 = packed[j + 7];
        uint4 r0 = h1bf[((long long)p0.x << 3) + lane];
        uint4 r1 = h1bf[((long long)p1.x << 3) + lane];
        uint4 r2 = h1bf[((long long)p2.x << 3) + lane];
        uint4 r3 = h1bf[((long long)p3.x << 3) + lane];
        uint4 r4 = h1bf[((long long)p4.x << 3) + lane];
        uint4 r5 = h1bf[((long long)p5.x << 3) + lane];
        uint4 r6 = h1bf[((long long)p6.x << 3) + lane];
        uint4 r7 = h1bf[((long long)p7.x << 3) + lane];
        EDGE_FMA(r0, __int_as_float(p0.y), a0, a1, a2, a3, a4, a5, a6, a7);
        EDGE_FMA(r1, __int_as_float(p1.y), b0, b1, b2, b3, b4, b5, b6, b7);
        EDGE_FMA(r2, __int_as_float(p2.y), a0, a1, a2, a3, a4, a5, a6, a7);
        EDGE_FMA(r3, __int_as_float(p3.y), b0, b1, b2, b3, b4, b5, b6, b7);
        EDGE_FMA(r4, __int_as_float(p4.y), a0, a1, a2, a3, a4, a5, a6, a7);
        EDGE_FMA(r5, __int_as_float(p5.y), b0, b1, b2, b3, b4, b5, b6, b7);
        EDGE_FMA(r6, __int_as_float(p6.y), a0, a1, a2, a3, a4, a5, a6, a7);
        EDGE_FMA(r7, __int_as_float(p7.y), b0, b1, b2, b3, b4, b5, b6, b7);
    }
    for (; j + 4 <= end; j += 4) {
        int2 p0 = packed[j + 0], p1 = packed[j + 1], p2 = packed[j + 2], p3 = packed[j + 3];
        uint4 r0 = h1bf[((long long)p0.x << 3) + lane];
        uint4 r1 = h1bf[((long long)p1.x << 3) + lane];
        uint4 r2 = h1bf[((long long)p2.x << 3) + lane];
        uint4 r3 = h1bf[((long long)p3.x << 3) + lane];
        EDGE_FMA(r0, __int_as_float(p0.y), a0, a1, a2, a3, a4, a5, a6, a7);
        EDGE_FMA(r1, __int_as_float(p1.y), b0, b1, b2, b3, b4, b5, b6, b7);
        EDGE_FMA(r2, __int_as_float(p2.y), a0, a1, a2, a3, a4, a5, a6, a7);
        EDGE_FMA(r3, __int_as_float(p3.y), b0, b1, b2, b3, b4, b5, b6, b7);
    }
    for (; j < end; ++j) {
        int2 p = packed[j];
        uint4 r = h1bf[((long long)p.x << 3) + lane];
        EDGE_FMA(r, __int_as_float(p.y), a0, a1, a2, a3, a4, a5, a6, a7);
    }
    long long idx = ((long long)node << 3) + lane;
    float nv = norm[node];
    uint4 h0r = h0bf[idx], h1r = h1bf[idx];
    float2 h0a = bfpair(h0r.x), h0b = bfpair(h0r.y), h0c = bfpair(h0r.z), h0d = bfpair(h0r.w);
    float2 h1a = bfpair(h1r.x), h1b = bfpair(h1r.y), h1c = bfpair(h1r.z), h1d = bfpair(h1r.w);
    float4 o0, o1;
    o0.x = (h0a.x + h1a.x + (a0 + b0) * nv) * (1.0f / 3.0f);
    o0.y = (h0a.y + h1a.y + (a1 + b1) * nv) * (1.0f / 3.0f);
    o0.z = (h0b.x + h1b.x + (a2 + b2) * nv) * (1.0f / 3.0f);
    o0.w = (h0b.y + h1b.y + (a3 + b3) * nv) * (1.0f / 3.0f);
    o1.x = (h0c.x + h1c.x + (a4 + b4) * nv) * (1.0f / 3.0f);
    o1.y = (h0c.y + h1c.y + (a5 + b5) * nv) * (1.0f / 3.0f);
    o1.z = (h0d.x + h1d.x + (a6 + b6) * nv) * (1.0f / 3.0f);
    o1.w = (h0d.y + h1d.y + (a7 + b7) * nv) * (1.0f / 3.0f);
    ((float4*)out)[((long long)node << 4) + (lane << 1)] = o0;
    ((float4*)out)[((long long)node << 4) + (lane << 1) + 1] = o1;
}

extern "C" void kernel_launch(void* const* d_in, const int* in_sizes, int n_in,
                              void* d_out, int out_size, void* d_ws, size_t ws_size,
                              hipStream_t stream) {
    const float* h   = (const float*)d_in[0];
    const float* w   = (const float*)d_in[1];
    const int*   src = (const int*)d_in[2];
    const int*   dst = (const int*)d_in[3];
    const int N = in_sizes[0] / D;   // 100000
    const int E = in_sizes[1];       // 1600000
    float* out = (float*)d_out;

    const int B = (N + BKT_NODES - 1) >> BKT_BITS;   // 196 (<= 256 required)
    const int NBLK = (E + CHUNK - 1) / CHUNK;        // 196

    // ---- workspace layout ----
    char* ws = (char*)d_ws;
    size_t off = 0;
    auto alloc = [&](size_t bytes, size_t align) -> char* {
        off = (off + align - 1) & ~(align - 1);
        char* p = ws + off;
        off += bytes;
        return p;
    };
    float* norm     = (float*)alloc((size_t)N * 4, 16);
    int*   rowptr   = (int*)  alloc((size_t)(N + 1) * 4, 16);
    int*   total    = (int*)  alloc((size_t)B * 4, 16);
    int*   bstart   = (int*)  alloc((size_t)(B + 1) * 4, 16);
    int*   blockCnt = (int*)  alloc((size_t)NBLK * B * 4, 16);
    int2*  packed   = (int2*) alloc((size_t)E * 8, 16);
    // temp (build phase) time-shares with h1bf (gather phase), both 12.8 MB
    char*  shared_region = alloc((size_t)E * 8, 128);
    int2*     temp = (int2*)shared_region;
    unsigned* h1bf = (unsigned*)shared_region;
    unsigned* h0bf = (unsigned*)alloc((size_t)N * D * 2, 128);

    const int nodes_per_block = THREADS / 8;         // 8 lanes per node
    const int gather_blocks = (N + nodes_per_block - 1) / nodes_per_block;
    const long long nd4 = (long long)N * D / 4;
    const int cvt_blocks = (int)((nd4 + THREADS - 1) / THREADS);

    // CSR build: zero global atomics (LDS counting sort, 2 passes)
    p1a_hist<<<NBLK, THREADS, 0, stream>>>(dst, blockCnt, E, B);
    p1b_scanblocks<<<B, 256, 0, stream>>>(blockCnt, total, NBLK, B);
    p1c_scanbuckets<<<1, 256, 0, stream>>>(total, bstart, B, E);
    p1d_scatter<<<NBLK, THREADS, 0, stream>>>(dst, src, w, blockCnt, bstart, temp, E, B);
    p2a_build<<<B, 256, 0, stream>>>(temp, bstart, rowptr, norm, N, E, B);
    p2b_place<<<B, 256, 0, stream>>>(temp, bstart, rowptr, norm, packed, N, E);

    // h -> bf16
    tobf16_kernel<<<cvt_blocks, THREADS, 0, stream>>>(h, h0bf, nd4);

    // gathers (coef = w*norm[src] pre-folded; 8-lane/uint4, unroll-8 for deep MLP)
    gather1_kernel<<<gather_blocks, THREADS, 0, stream>>>((const uint4*)h0bf, packed, rowptr,
                                                          norm, (uint4*)h1bf, N);
    gather2_final_kernel<<<gather_blocks, THREADS, 0, stream>>>((const uint4*)h0bf, (const uint4*)h1bf,
                                                                packed, rowptr, norm, out, N);
}